// Round 7
// baseline (309.924 us; speedup 1.0000x reference)
//
#include <hip/hip_runtime.h>
#include <cstdint>
#include <cstddef>

// Problem constants (B,S,D,H fixed by the reference)
#define BB 2
#define SS 2048
#define DD 1024
#define HH 16
#define DHH 64
#define MROWS (BB*SS)   // 4096

typedef short short8 __attribute__((ext_vector_type(8)));
typedef short short4v __attribute__((ext_vector_type(4)));
typedef float floatx4 __attribute__((ext_vector_type(4)));

#define GAS __attribute__((address_space(1)))
#define LAS __attribute__((address_space(3)))

// 16x16x16 bf16 MFMA (A/B = 4 bf16 = 2 VGPRs; ISA: v_mfma_f32_16x16x16_bf16).
// IMPORTANT: __has_builtin for amdgcn target builtins returns 0 in the HOST
// pass of hip compilation — guard with __HIP_DEVICE_COMPILE__ and give the
// host pass a parse-only dummy (device bodies are never codegen'd for host).
#if !defined(__HIP_DEVICE_COMPILE__)
#define MFMA16(a, b, c) (c)   // host parse-only
#elif __has_builtin(__builtin_amdgcn_mfma_f32_16x16x16bf16_1k)
#define MFMA16(a, b, c) __builtin_amdgcn_mfma_f32_16x16x16bf16_1k((a), (b), (c), 0, 0, 0)
#elif __has_builtin(__builtin_amdgcn_mfma_f32_16x16x16_bf16)
#define MFMA16(a, b, c) __builtin_amdgcn_mfma_f32_16x16x16_bf16((a), (b), (c), 0, 0, 0)
#elif __has_builtin(__builtin_amdgcn_mfma_f32_16x16x16_bf16_1k)
#define MFMA16(a, b, c) __builtin_amdgcn_mfma_f32_16x16x16_bf16_1k((a), (b), (c), 0, 0, 0)
#else
#error "no 16x16x16 bf16 MFMA builtin found on device pass"
#endif

__device__ __forceinline__ float4 ld4(const float* p) { return *(const float4*)p; }

// RNE float -> bf16 bits (no NaN inputs here)
__device__ __forceinline__ short f2bf(float x) {
    unsigned u = __builtin_bit_cast(unsigned, x);
    unsigned r = (u + 0x7fffu + ((u >> 16) & 1u)) >> 16;
    return (short)r;
}

// async global->LDS, 16B per lane; LDS dest must be lane-contiguous per wave
__device__ __forceinline__ void gl_lds16(const short* g, short* l) {
    __builtin_amdgcn_global_load_lds((const GAS unsigned int*)g,
                                     (LAS unsigned int*)l, 16, 0, 0);
}

// ---------------------------------------------------------------------------
// Weight transpose-convert: T[n][k] = bf16(W[k][n]), 1024x1024, 64x64 tiles.
// grid = (16, 16, 4)
// ---------------------------------------------------------------------------
__global__ __launch_bounds__(256) void transpose_w_kernel(
    const float* __restrict__ W0, const float* __restrict__ W1,
    const float* __restrict__ W2, const float* __restrict__ W3,
    short* __restrict__ T0, short* __restrict__ T1,
    short* __restrict__ T2, short* __restrict__ T3)
{
    const float* W; short* T;
    if (blockIdx.z == 0)      { W = W0; T = T0; }
    else if (blockIdx.z == 1) { W = W1; T = T1; }
    else if (blockIdx.z == 2) { W = W2; T = T2; }
    else                      { W = W3; T = T3; }

    __shared__ short tile[64 * 72];   // [n][k], stride 72 shorts
    const int t  = threadIdx.x;
    const int k0 = blockIdx.x * 64, n0 = blockIdx.y * 64;
#pragma unroll
    for (int i = 0; i < 4; i++) {
        int flat = i * 256 + t;              // float4 units
        int row = flat >> 4;                 // k within tile
        int c4  = (flat & 15) * 4;           // n within tile
        float4 v = ld4(W + (size_t)(k0 + row) * DD + n0 + c4);
        tile[(c4 + 0) * 72 + row] = f2bf(v.x);
        tile[(c4 + 1) * 72 + row] = f2bf(v.y);
        tile[(c4 + 2) * 72 + row] = f2bf(v.z);
        tile[(c4 + 3) * 72 + row] = f2bf(v.w);
    }
    __syncthreads();
#pragma unroll
    for (int i = 0; i < 4; i++) {
        int flat = i * 256 + t;              // short4 units
        int nrow = flat >> 4;
        int kc   = (flat & 15) * 4;
        short4v pk = *(short4v*)&tile[nrow * 72 + kc];
        *(short4v*)(T + (size_t)(n0 + nrow) * DD + k0 + kc) = pk;
    }
}

// ---------------------------------------------------------------------------
// BF16 MFMA GEMM, restructured K-loop: C[M,N] = bf16(A_f32)[M,K] @ Bt[N,K]^T
// + bias. Tile 128x128, 256 thr (4 waves), wave=64x64, BK=32.
//  - A (fp32) prefetched to registers, converted to bf16 at commit time
//    (fp32->bf16 convert folded into staging; no separate convert kernel).
//  - B (bf16) staged via global_load_lds into the *other* buffer, issued
//    after the barrier -> loads overlap the whole compute phase; the vmcnt
//    wait lands at the next A-commit, one full iteration after issue.
//  - Double-buffered LDS, one __syncthreads per K-iter.
// Epilogue per z: optional fp32 Cf, bf16 Cb (scaled), bf16 transposed Ct
// (Ct layout: [(b*1024 + h*64+d)][s] for the attention V operand).
// grid = (8, 32, nz)
// ---------------------------------------------------------------------------
__global__ __launch_bounds__(256) void gemm_bf16_kernel(
    const float* __restrict__ A0, const float* __restrict__ A1, const float* __restrict__ A2,
    const short* __restrict__ Bt0, const short* __restrict__ Bt1, const short* __restrict__ Bt2,
    const float* __restrict__ b0, const float* __restrict__ b1, const float* __restrict__ b2,
    float* __restrict__ Cf0, float* __restrict__ Cf1, float* __restrict__ Cf2,
    short* __restrict__ Cb0, short* __restrict__ Cb1, short* __restrict__ Cb2,
    short* __restrict__ Ct0, short* __restrict__ Ct1, short* __restrict__ Ct2,
    float cs0, float cs1, float cs2)
{
    const float* A; const short* Bt; const float* bias;
    float* Cf; short* Cb; short* Ct; float cbs;
    if (blockIdx.z == 0)      { A = A0; Bt = Bt0; bias = b0; Cf = Cf0; Cb = Cb0; Ct = Ct0; cbs = cs0; }
    else if (blockIdx.z == 1) { A = A1; Bt = Bt1; bias = b1; Cf = Cf1; Cb = Cb1; Ct = Ct1; cbs = cs1; }
    else                      { A = A2; Bt = Bt2; bias = b2; Cf = Cf2; Cb = Cb2; Ct = Ct2; cbs = cs2; }

    __shared__ __align__(16) short As[2 * 128 * 32];
    __shared__ __align__(16) short Bs[2 * 128 * 32];

    const int tid  = threadIdx.x;
    const int lane = tid & 63;
    const int wave = tid >> 6;
    const int quad = lane >> 4;
    const int l15  = lane & 15;
    const int m0 = blockIdx.y * 128;
    const int n0 = blockIdx.x * 128;
    const int wr = (wave >> 1) * 64;   // wave m-offset
    const int wc = (wave & 1) * 64;    // wave n-offset

    const int arow = tid >> 2;         // A staging: row (+64 for i=1)
    const int ach  = tid & 3;          // 8-float chunk within 32-k row

    floatx4 acc[4][4];
#pragma unroll
    for (int mt = 0; mt < 4; mt++)
#pragma unroll
        for (int nt = 0; nt < 4; nt++) acc[mt][nt] = (floatx4)0.0f;

    float4 fa[2][2];
    // preamble: B(0) via gl_lds into buf0, A(0) into regs
#pragma unroll
    for (int i = 0; i < 2; i++) {
        int c = tid + i * 256;
        gl_lds16(Bt + (size_t)(n0 + (c >> 2)) * DD + (c & 3) * 8, &Bs[c * 8]);
    }
#pragma unroll
    for (int i = 0; i < 2; i++) {
        const float* ap = A + (size_t)(m0 + arow + i * 64) * DD + ach * 8;
        fa[i][0] = ld4(ap);
        fa[i][1] = ld4(ap + 4);
    }

    for (int kk = 0; kk < 32; kk++) {
        const int bufo = (kk & 1) * 4096;
        // commit A(kk): convert + ds_write (implicit vmcnt wait on fa here)
#pragma unroll
        for (int i = 0; i < 2; i++) {
            short8 s8;
            s8[0] = f2bf(fa[i][0].x); s8[1] = f2bf(fa[i][0].y);
            s8[2] = f2bf(fa[i][0].z); s8[3] = f2bf(fa[i][0].w);
            s8[4] = f2bf(fa[i][1].x); s8[5] = f2bf(fa[i][1].y);
            s8[6] = f2bf(fa[i][1].z); s8[7] = f2bf(fa[i][1].w);
            *(short8*)&As[bufo + (arow + i * 64) * 32 + ach * 8] = s8;
        }
        __syncthreads();

        if (kk < 31) {
            const int k0n = (kk + 1) * 32;
            const int nbuf = bufo ^ 4096;
#pragma unroll
            for (int i = 0; i < 2; i++) {
                int c = tid + i * 256;
                gl_lds16(Bt + (size_t)(n0 + (c >> 2)) * DD + k0n + (c & 3) * 8,
                         &Bs[nbuf + c * 8]);
            }
#pragma unroll
            for (int i = 0; i < 2; i++) {
                const float* ap = A + (size_t)(m0 + arow + i * 64) * DD + k0n + ach * 8;
                fa[i][0] = ld4(ap);
                fa[i][1] = ld4(ap + 4);
            }
        }

        short8 af[4], bf[4];
#pragma unroll
        for (int mt = 0; mt < 4; mt++)
            af[mt] = *(const short8*)&As[bufo + (wr + mt * 16 + l15) * 32 + quad * 8];
#pragma unroll
        for (int nt = 0; nt < 4; nt++)
            bf[nt] = *(const short8*)&Bs[bufo + (wc + nt * 16 + l15) * 32 + quad * 8];
#pragma unroll
        for (int mt = 0; mt < 4; mt++)
#pragma unroll
            for (int nt = 0; nt < 4; nt++)
                acc[mt][nt] = __builtin_amdgcn_mfma_f32_16x16x32_bf16(af[mt], bf[nt], acc[mt][nt], 0, 0, 0);
    }

    float biasv[4];
#pragma unroll
    for (int nt = 0; nt < 4; nt++) biasv[nt] = bias[n0 + wc + nt * 16 + l15];

    if (Cf || Cb) {
#pragma unroll
        for (int mt = 0; mt < 4; mt++)
#pragma unroll
            for (int r = 0; r < 4; r++) {
                const int m = m0 + wr + mt * 16 + quad * 4 + r;
                const size_t rowb = (size_t)m * DD + n0 + wc;
#pragma unroll
                for (int nt = 0; nt < 4; nt++) {
                    float v = acc[mt][nt][r] + biasv[nt];
                    if (Cf) Cf[rowb + nt * 16 + l15] = v;
                    if (Cb) Cb[rowb + nt * 16 + l15] = f2bf(v * cbs);
                }
            }
    }
    if (Ct) {
#pragma unroll
        for (int mt = 0; mt < 4; mt++) {
            const int mbase = m0 + wr + mt * 16 + quad * 4;
            const int bb = mbase >> 11;       // batch (tiles don't cross batch)
            const int s0 = mbase & 2047;
#pragma unroll
            for (int nt = 0; nt < 4; nt++) {
                const int c = n0 + wc + nt * 16 + l15;   // = h*64 + d
                short4v pk;
#pragma unroll
                for (int r = 0; r < 4; r++) pk[r] = f2bf(acc[mt][nt][r] + biasv[nt]);
                *(short4v*)(Ct + ((size_t)(bb * 1024 + c)) * SS + s0) = pk;
            }
        }
    }
}

// ---------------------------------------------------------------------------
// BF16 MFMA attention, operand-swapped (no P LDS round-trip):
//   S^T = K @ Q^T   via mfma_16x16x32 (A=K-frag from LDS, B=Q-frag in regs)
//   P^T = exp(S^T) * mask   — C-layout (row=key=quad*4+r, col=query=l15)
//     is bit-identical to the 16x16x16 MFMA B-fragment layout (k=quad*4+j),
//     so P feeds PV directly from registers (pack to bf16 only).
//   O^T = V^T @ P^T via mfma_16x16x16 (A=V^T-frag from Vs [d][key]).
// Absolute-exp softmax (Q pre-scaled 1/8; masked p -> 0 via *mask).
// 256 thr / 4 waves, 128-query tile, wave = 32 q (2 qt of 16).
// Double-buffered K/V + reg prefetch, lgkm-only barrier (proven r5 scheme).
// LDS 37.4 KB -> 4 blocks/CU. Fuses +q residual & per-head LN. fp32 X out.
// grid = (S/128=16, H=16, B=2)
// ---------------------------------------------------------------------------
__global__ __launch_bounds__(256, 4) void attn_mfma_kernel(
    const short* __restrict__ Qb, const short* __restrict__ Kb, const short* __restrict__ Vt,
    const float* __restrict__ Qf, const int* __restrict__ mask,
    const float* __restrict__ g_att, const float* __restrict__ b_att,
    float* __restrict__ X)
{
    const int tid  = threadIdx.x;
    const int lane = tid & 63;
    const int wave = tid >> 6;          // 0..3
    const int quad = lane >> 4;
    const int l15  = lane & 15;

    const int h  = blockIdx.y;
    const int b  = blockIdx.z;
    const int q0 = blockIdx.x * 128;
    const int bS = b * SS;

    __shared__ __align__(16) short Ks[2 * 64 * 72];   // [buf][key][d]
    __shared__ __align__(16) short Vs[2 * 64 * 72];   // [buf][d][key]
    __shared__ __align__(16) float smv[2 * 64];       // [buf][key] mask 0/1

    // Q fragments (bf16, pre-scaled 1/8) — serve as MFMA B operand for S^T
    short8 qf[2][2];
#pragma unroll
    for (int qt = 0; qt < 2; qt++)
#pragma unroll
        for (int s = 0; s < 2; s++)
            qf[qt][s] = *(const short8*)(Qb +
                (size_t)(bS + q0 + wave * 32 + qt * 16 + l15) * DD + h * 64 + s * 32 + quad * 8);

    floatx4 o[4][2];                    // O^T tiles [dt][qt]
#pragma unroll
    for (int dt = 0; dt < 4; dt++)
#pragma unroll
        for (int qt = 0; qt < 2; qt++) o[dt][qt] = (floatx4)0.0f;
    float lsum[2] = {0.0f, 0.0f};

    const int srow = tid >> 3;          // staging row (+32 for i=1)
    const int sch  = tid & 7;

    // preload tile 0 into regs
    short8 kreg[2], vreg[2];
    float mreg;
#pragma unroll
    for (int i = 0; i < 2; i++) {
        int row = srow + i * 32;
        kreg[i] = *(const short8*)(Kb + (size_t)(bS + row) * DD + h * 64 + sch * 8);
        vreg[i] = *(const short8*)(Vt + (size_t)(b * 1024 + h * 64 + row) * SS + sch * 8);
    }
    mreg = (tid < 64) ? (float)mask[bS + tid] : 0.0f;

    for (int kt = 0; kt < SS / 64; kt++) {
        const int bufo = (kt & 1) * (64 * 72);
        const int mvo  = (kt & 1) * 64;
        // commit staged regs for tile kt (implicit vmcnt wait on kreg/vreg)
#pragma unroll
        for (int i = 0; i < 2; i++) {
            int row = srow + i * 32;
            *(short8*)&Ks[bufo + row * 72 + sch * 8] = kreg[i];
            *(short8*)&Vs[bufo + row * 72 + sch * 8] = vreg[i];
        }
        if (tid < 64) smv[mvo + tid] = mreg;

        // prefetch tile kt+1 (stays in flight across the barrier)
        if (kt < SS / 64 - 1) {
            const int k0n = (kt + 1) * 64;
#pragma unroll
            for (int i = 0; i < 2; i++) {
                int row = srow + i * 32;
                kreg[i] = *(const short8*)(Kb + (size_t)(bS + k0n + row) * DD + h * 64 + sch * 8);
                vreg[i] = *(const short8*)(Vt + (size_t)(b * 1024 + h * 64 + row) * SS + k0n + sch * 8);
            }
            mreg = (tid < 64) ? (float)mask[bS + k0n + tid] : 0.0f;
        }

        // raw barrier: drain LDS writes only; vmcnt stays in flight
        __builtin_amdgcn_s_waitcnt(0xC07F);
        __builtin_amdgcn_s_barrier();

        // S^T = K @ Q^T, P^T = exp(.)*mask, pack to 16x16x16 B-frags
        short4v pf[4][2];               // [kstep=kt4][qt]
#pragma unroll
        for (int kt4 = 0; kt4 < 4; kt4++) {
            short8 kf0 = *(const short8*)&Ks[bufo + (kt4 * 16 + l15) * 72 + quad * 8];
            short8 kf1 = *(const short8*)&Ks[bufo + (kt4 * 16 + l15) * 72 + 32 + quad * 8];
            floatx4 mv = *(const floatx4*)&smv[mvo + kt4 * 16 + quad * 4];
#pragma unroll
            for (int qt = 0; qt < 2; qt++) {
                floatx4 st = (floatx4)0.0f;
                st = __builtin_amdgcn_mfma_f32_16x16x32_bf16(kf0, qf[qt][0], st, 0, 0, 0);
                st = __builtin_amdgcn_mfma_f32_16x16x32_bf16(kf1, qf[qt][1], st, 0, 0, 0);
                short4v pk;
#pragma unroll
                for (int r = 0; r < 4; r++) {
                    float p = __expf(st[r]) * mv[r];
                    lsum[qt] += p;
                    pk[r] = f2bf(p);
                }
                pf[kt4][qt] = pk;
            }
        }

        // O^T += V^T @ P^T  (P straight from registers)
#pragma unroll
        for (int dt = 0; dt < 4; dt++)
#pragma unroll
            for (int ks = 0; ks < 4; ks++) {
                short4v vf = *(const short4v*)&Vs[bufo + (dt * 16 + l15) * 72 + ks * 16 + quad * 4];
#pragma unroll
                for (int qt = 0; qt < 2; qt++)
                    o[dt][qt] = MFMA16(vf, pf[ks][qt], o[dt][qt]);
            }
    }

    // softmax denominators: complete the key-sum across quads
#pragma unroll
    for (int qt = 0; qt < 2; qt++) {
        lsum[qt] += __shfl_xor(lsum[qt], 16);
        lsum[qt] += __shfl_xor(lsum[qt], 32);
    }

    // epilogue: O/l + residual q (fp32), per-head LayerNorm over d=64
#pragma unroll
    for (int qt = 0; qt < 2; qt++) {
        const int q = q0 + wave * 32 + qt * 16 + l15;
        const size_t base = (size_t)(bS + q) * DD + h * 64;
        const float rl = 1.0f / lsum[qt];

        float x[4][4];
        float sum = 0.0f;
#pragma unroll
        for (int dt = 0; dt < 4; dt++) {
            float4 qr = ld4(Qf + base + dt * 16 + quad * 4);
            x[dt][0] = o[dt][qt][0] * rl + qr.x;
            x[dt][1] = o[dt][qt][1] * rl + qr.y;
            x[dt][2] = o[dt][qt][2] * rl + qr.z;
            x[dt][3] = o[dt][qt][3] * rl + qr.w;
            sum += x[dt][0] + x[dt][1] + x[dt][2] + x[dt][3];
        }
        sum += __shfl_xor(sum, 16);
        sum += __shfl_xor(sum, 32);
        const float mu = sum * (1.0f / 64.0f);

        float vs = 0.0f;
#pragma unroll
        for (int dt = 0; dt < 4; dt++)
#pragma unroll
            for (int r = 0; r < 4; r++) { float d = x[dt][r] - mu; vs += d * d; }
        vs += __shfl_xor(vs, 16);
        vs += __shfl_xor(vs, 32);
        const float rstd = rsqrtf(vs * (1.0f / 64.0f) + 1e-5f);

#pragma unroll
        for (int dt = 0; dt < 4; dt++) {
            float4 gv = ld4(g_att + dt * 16 + quad * 4);
            float4 bv = ld4(b_att + dt * 16 + quad * 4);
            float4 y;
            y.x = (x[dt][0] - mu) * rstd * gv.x + bv.x;
            y.y = (x[dt][1] - mu) * rstd * gv.y + bv.y;
            y.z = (x[dt][2] - mu) * rstd * gv.z + bv.z;
            y.w = (x[dt][3] - mu) * rstd * gv.w + bv.w;
            *(float4*)(X + base + dt * 16 + quad * 4) = y;
        }
    }
}

// ---------------------------------------------------------------------------
// Final fused epilogue: Z = X + tanh(Y);  out = tanh(LayerNorm(Z, g, b))
// ---------------------------------------------------------------------------
__global__ __launch_bounds__(256) void lnout_kernel(
    const float* __restrict__ X, const float* __restrict__ Y,
    const float* __restrict__ g, const float* __restrict__ bcoef,
    float* __restrict__ out)
{
    const int r = blockIdx.x;
    const int t = threadIdx.x;
    const size_t base = (size_t)r * DD + (t << 2);
    float4 x = ld4(X + base);
    float4 y = ld4(Y + base);
    float4 z;
    z.x = x.x + tanhf(y.x);
    z.y = x.y + tanhf(y.y);
    z.z = x.z + tanhf(y.z);
    z.w = x.w + tanhf(y.w);

    __shared__ float red[4];
    __shared__ float stats[2];
    const int w = t >> 6;

    float sv = z.x + z.y + z.z + z.w;
#pragma unroll
    for (int off = 32; off > 0; off >>= 1) sv += __shfl_down(sv, off);
    if ((t & 63) == 0) red[w] = sv;
    __syncthreads();
    if (t == 0) stats[0] = (red[0] + red[1] + red[2] + red[3]) * (1.0f / 1024.0f);
    __syncthreads();
    const float mu = stats[0];

    float4 d;
    d.x = z.x - mu; d.y = z.y - mu; d.z = z.z - mu; d.w = z.w - mu;
    float s2 = d.x * d.x + d.y * d.y + d.z * d.z + d.w * d.w;
#pragma unroll
    for (int off = 32; off > 0; off >>= 1) s2 += __shfl_down(s2, off);
    if ((t & 63) == 0) red[w] = s2;
    __syncthreads();
    if (t == 0) stats[1] = rsqrtf((red[0] + red[1] + red[2] + red[3]) * (1.0f / 1024.0f) + 1e-5f);
    __syncthreads();
    const float rstd = stats[1];

    float4 gv = ld4(g + (t << 2));
    float4 bv = ld4(bcoef + (t << 2));
    float4 o;
    o.x = tanhf(d.x * rstd * gv.x + bv.x);
    o.y = tanhf(d.y * rstd * gv.y + bv.y);
    o.z = tanhf(d.z * rstd * gv.z + bv.z);
    o.w = tanhf(d.w * rstd * gv.w + bv.w);
    *(float4*)(out + base) = o;
}

// ---------------------------------------------------------------------------
extern "C" void kernel_launch(void* const* d_in, const int* in_sizes, int n_in,
                              void* d_out, int out_size, void* d_ws, size_t ws_size,
                              hipStream_t stream)
{
    const float* query = (const float*)d_in[0];
    const float* key   = (const float*)d_in[1];
    const float* value = (const float*)d_in[2];
    const int*   mask  = (const int*)  d_in[3];
    const float* Wq    = (const float*)d_in[4];
    const float* bq    = (const float*)d_in[5];
    const float* Wk    = (const float*)d_in[6];
    const float* bk    = (const float*)d_in[7];
    const float* Wv    = (const float*)d_in[8];
    const float* bv    = (const float*)d_in[9];
    const float* g_att = (const float*)d_in[10];
    const float* b_att = (const float*)d_in[11];
    const float* Wres  = (const float*)d_in[12];
    const float* bres  = (const float*)d_in[13];
    const float* g_out = (const float*)d_in[14];
    const float* b_out = (const float*)d_in[15];

    const size_t MAT = (size_t)MROWS * DD;     // 4M elements
    float* fws = (float*)d_ws;
    float* Qw = fws;                           // fp32 Q residual
    float* Xw = fws + MAT;                     // attn out fp32
    float* Yw = fws + 2 * MAT;                 // res GEMM fp32 out
    short* Qb = (short*)(fws + 3 * MAT);       // bf16 Q/8
    short* Kb = Qb + MAT;
    short* Vt = Kb + MAT;                      // V^T [(b*1024+h*64+d)][S]
    short* Wtq = Vt + MAT;                     // weight transposes (1M shorts ea)
    short* Wtk = Wtq + DD * DD;
    short* Wtv = Wtk + DD * DD;
    short* Wtr = Wtv + DD * DD;

    // 1) weight transpose-converts
    transpose_w_kernel<<<dim3(16, 16, 4), 256, 0, stream>>>(
        Wq, Wk, Wv, Wres, Wtq, Wtk, Wtv, Wtr);

    // 2) QKV projections (fp32 A in, convert folded into staging).
    //    Q: fp32 + bf16*(1/8); K: bf16; V: bf16^T
    gemm_bf16_kernel<<<dim3(8, 32, 3), 256, 0, stream>>>(
        query, key, value, Wtq, Wtk, Wtv, bq, bk, bv,
        Qw, nullptr, nullptr,
        Qb, Kb, nullptr,
        nullptr, nullptr, Vt,
        0.125f, 1.0f, 1.0f);

    // 3) bf16 MFMA attention (operand-swapped, P in registers) + res + LN
    attn_mfma_kernel<<<dim3(SS / 128, HH, BB), 256, 0, stream>>>(
        Qb, Kb, Vt, Qw, mask, g_att, b_att, Xw);

    // 4) res branch GEMM: Yw = bf16(Xw) @ Wres + bres (fp32 out)
    gemm_bf16_kernel<<<dim3(8, 32, 1), 256, 0, stream>>>(
        Xw, Xw, Xw, Wtr, Wtr, Wtr, bres, bres, bres,
        Yw, Yw, Yw, nullptr, nullptr, nullptr, nullptr, nullptr, nullptr,
        1.0f, 1.0f, 1.0f);

    // 5) Z = X + tanh(Y); out = tanh(LN(Z))
    lnout_kernel<<<MROWS, 256, 0, stream>>>(Xw, Yw, g_out, b_out, (float*)d_out);
}

// Round 8
// 290.309 us; speedup vs baseline: 1.0676x; 1.0676x over previous
//
#include <hip/hip_runtime.h>
#include <cstdint>
#include <cstddef>

// Problem constants (B,S,D,H fixed by the reference)
#define BB 2
#define SS 2048
#define DD 1024
#define HH 16
#define DHH 64
#define MROWS (BB*SS)   // 4096

typedef short short8 __attribute__((ext_vector_type(8)));
typedef short short4v __attribute__((ext_vector_type(4)));
typedef float floatx4 __attribute__((ext_vector_type(4)));

#define GAS __attribute__((address_space(1)))
#define LAS __attribute__((address_space(3)))

__device__ __forceinline__ float4 ld4(const float* p) { return *(const float4*)p; }

// RNE float -> bf16 bits (no NaN inputs here)
__device__ __forceinline__ short f2bf(float x) {
    unsigned u = __builtin_bit_cast(unsigned, x);
    unsigned r = (u + 0x7fffu + ((u >> 16) & 1u)) >> 16;
    return (short)r;
}

// async global->LDS, 16B per lane; LDS dest must be lane-contiguous per wave
__device__ __forceinline__ void gl_lds16(const short* g, short* l) {
    __builtin_amdgcn_global_load_lds((const GAS unsigned int*)g,
                                     (LAS unsigned int*)l, 16, 0, 0);
}

// ---------------------------------------------------------------------------
// fp32 -> bf16 row-major convert (query/key/value), 8 elems/thread
// grid = (MROWS*DD/2048, 1, 3)
// ---------------------------------------------------------------------------
__global__ __launch_bounds__(256) void convert_kernel(
    const float* __restrict__ s0, const float* __restrict__ s1, const float* __restrict__ s2,
    short* __restrict__ d0, short* __restrict__ d1, short* __restrict__ d2)
{
    const float* s; short* d;
    if (blockIdx.z == 0)      { s = s0; d = d0; }
    else if (blockIdx.z == 1) { s = s1; d = d1; }
    else                      { s = s2; d = d2; }
    size_t idx = ((size_t)blockIdx.x * 256 + threadIdx.x) * 8;
    float4 a = ld4(s + idx);
    float4 b = ld4(s + idx + 4);
    short8 p;
    p[0] = f2bf(a.x); p[1] = f2bf(a.y); p[2] = f2bf(a.z); p[3] = f2bf(a.w);
    p[4] = f2bf(b.x); p[5] = f2bf(b.y); p[6] = f2bf(b.z); p[7] = f2bf(b.w);
    *(short8*)(d + idx) = p;
}

// ---------------------------------------------------------------------------
// Weight transpose-convert: T[n][k] = bf16(W[k][n]), 1024x1024, 64x64 tiles.
// grid = (16, 16, 4)
// ---------------------------------------------------------------------------
__global__ __launch_bounds__(256) void transpose_w_kernel(
    const float* __restrict__ W0, const float* __restrict__ W1,
    const float* __restrict__ W2, const float* __restrict__ W3,
    short* __restrict__ T0, short* __restrict__ T1,
    short* __restrict__ T2, short* __restrict__ T3)
{
    const float* W; short* T;
    if (blockIdx.z == 0)      { W = W0; T = T0; }
    else if (blockIdx.z == 1) { W = W1; T = T1; }
    else if (blockIdx.z == 2) { W = W2; T = T2; }
    else                      { W = W3; T = T3; }

    __shared__ short tile[64 * 72];   // [n][k], stride 72 shorts
    const int t  = threadIdx.x;
    const int k0 = blockIdx.x * 64, n0 = blockIdx.y * 64;
#pragma unroll
    for (int i = 0; i < 4; i++) {
        int flat = i * 256 + t;              // float4 units
        int row = flat >> 4;                 // k within tile
        int c4  = (flat & 15) * 4;           // n within tile
        float4 v = ld4(W + (size_t)(k0 + row) * DD + n0 + c4);
        tile[(c4 + 0) * 72 + row] = f2bf(v.x);
        tile[(c4 + 1) * 72 + row] = f2bf(v.y);
        tile[(c4 + 2) * 72 + row] = f2bf(v.z);
        tile[(c4 + 3) * 72 + row] = f2bf(v.w);
    }
    __syncthreads();
#pragma unroll
    for (int i = 0; i < 4; i++) {
        int flat = i * 256 + t;              // short4 units
        int nrow = flat >> 4;
        int kc   = (flat & 15) * 4;
        short4v pk = *(short4v*)&tile[nrow * 72 + kc];
        *(short4v*)(T + (size_t)(n0 + nrow) * DD + k0 + kc) = pk;
    }
}

// ---------------------------------------------------------------------------
// V transpose: Vb row-major [(b*2048+s)][c] bf16 -> Vt [(b*1024+c)][s] bf16.
// 64x64 LDS tiles, coalesced b128 on both global sides (replaces the 8B/4KB
// scatter that the GEMM epilogue used to do -> ~4x write amplification).
// grid = (64 s-tiles, 16 c-tiles)
// ---------------------------------------------------------------------------
__global__ __launch_bounds__(256) void transpose_v_kernel(
    const short* __restrict__ Vb, short* __restrict__ Vt)
{
    __shared__ short tile[64 * 72];   // [c][s], stride 72
    const int t  = threadIdx.x;
    const int sb = blockIdx.x * 64;          // global row (b*2048+s)
    const int cb = blockIdx.y * 64;          // col
    const int b  = sb >> 11;
    const int s0 = sb & 2047;
#pragma unroll
    for (int i = 0; i < 2; i++) {
        int flat = i * 256 + t;              // short8 units (512 total)
        int r  = flat >> 3;                  // s within tile
        int ch = flat & 7;
        short8 v = *(const short8*)(Vb + (size_t)(sb + r) * DD + cb + ch * 8);
#pragma unroll
        for (int j = 0; j < 8; j++) tile[(ch * 8 + j) * 72 + r] = v[j];
    }
    __syncthreads();
#pragma unroll
    for (int i = 0; i < 2; i++) {
        int flat = i * 256 + t;
        int cr = flat >> 3;                  // c within tile
        int sc = flat & 7;
        short8 w = *(const short8*)&tile[cr * 72 + sc * 8];
        *(short8*)(Vt + ((size_t)(b * 1024 + cb + cr)) * SS + s0 + sc * 8) = w;
    }
}

// ---------------------------------------------------------------------------
// BF16 MFMA GEMM (proven r5/m97 structure): C[M,N] = A[M,K] @ Bt[N,K]^T + bias
// M=4096, N=K=1024. Tile 128x128, 256 thr (4 waves), wave=64x64, BK=32.
// Staging via global_load_lds width=16, LDS K-major, no padding.
// Epilogue per z: optional fp32 Cf, bf16 Cb (scaled by cs_z). Row-major only
// (the Vt transpose is a separate coalesced kernel now).
// grid = (8, 32, nz)
// ---------------------------------------------------------------------------
__global__ __launch_bounds__(256) void gemm_bf16_kernel(
    const short* __restrict__ A0, const short* __restrict__ A1, const short* __restrict__ A2,
    const short* __restrict__ Bt0, const short* __restrict__ Bt1, const short* __restrict__ Bt2,
    const float* __restrict__ b0, const float* __restrict__ b1, const float* __restrict__ b2,
    float* __restrict__ Cf0, float* __restrict__ Cf1, float* __restrict__ Cf2,
    short* __restrict__ Cb0, short* __restrict__ Cb1, short* __restrict__ Cb2,
    float cs0, float cs1, float cs2)
{
    const short* A; const short* Bt; const float* bias;
    float* Cf; short* Cb; float cbs;
    if (blockIdx.z == 0)      { A = A0; Bt = Bt0; bias = b0; Cf = Cf0; Cb = Cb0; cbs = cs0; }
    else if (blockIdx.z == 1) { A = A1; Bt = Bt1; bias = b1; Cf = Cf1; Cb = Cb1; cbs = cs1; }
    else                      { A = A2; Bt = Bt2; bias = b2; Cf = Cf2; Cb = Cb2; cbs = cs2; }

    __shared__ __align__(16) short As[128 * 32];
    __shared__ __align__(16) short Bs[128 * 32];

    const int tid  = threadIdx.x;
    const int lane = tid & 63;
    const int wave = tid >> 6;
    const int quad = lane >> 4;
    const int l15  = lane & 15;
    const int m0 = blockIdx.y * 128;
    const int n0 = blockIdx.x * 128;
    const int wr = (wave >> 1) * 64;   // wave m-offset
    const int wc = (wave & 1) * 64;    // wave n-offset

    floatx4 acc[4][4];
#pragma unroll
    for (int mt = 0; mt < 4; mt++)
#pragma unroll
        for (int nt = 0; nt < 4; nt++) acc[mt][nt] = (floatx4)0.0f;

    for (int k0 = 0; k0 < DD; k0 += 32) {
        __syncthreads();
#pragma unroll
        for (int j = 0; j < 2; j++) {
            int chunk = j * 256 + tid;        // 16B chunk id, lane-contiguous
            int row = chunk >> 2;             // tile row
            int ch  = chunk & 3;              // 8-elem chunk within 32-k row
            gl_lds16(A  + (size_t)(m0 + row) * DD + k0 + ch * 8, &As[chunk * 8]);
            gl_lds16(Bt + (size_t)(n0 + row) * DD + k0 + ch * 8, &Bs[chunk * 8]);
        }
        __syncthreads();

        short8 af[4], bf[4];
#pragma unroll
        for (int mt = 0; mt < 4; mt++)
            af[mt] = *(const short8*)&As[(wr + mt * 16 + l15) * 32 + quad * 8];
#pragma unroll
        for (int nt = 0; nt < 4; nt++)
            bf[nt] = *(const short8*)&Bs[(wc + nt * 16 + l15) * 32 + quad * 8];
#pragma unroll
        for (int mt = 0; mt < 4; mt++)
#pragma unroll
            for (int nt = 0; nt < 4; nt++)
                acc[mt][nt] = __builtin_amdgcn_mfma_f32_16x16x32_bf16(af[mt], bf[nt], acc[mt][nt], 0, 0, 0);
    }

    float biasv[4];
#pragma unroll
    for (int nt = 0; nt < 4; nt++) biasv[nt] = bias[n0 + wc + nt * 16 + l15];

#pragma unroll
    for (int mt = 0; mt < 4; mt++)
#pragma unroll
        for (int r = 0; r < 4; r++) {
            const int m = m0 + wr + mt * 16 + quad * 4 + r;
            const size_t rowb = (size_t)m * DD + n0 + wc;
#pragma unroll
            for (int nt = 0; nt < 4; nt++) {
                float v = acc[mt][nt][r] + biasv[nt];
                if (Cf) Cf[rowb + nt * 16 + l15] = v;
                if (Cb) Cb[rowb + nt * 16 + l15] = f2bf(v * cbs);
            }
        }
}

// ---------------------------------------------------------------------------
// BF16 MFMA attention, operand-swapped with full-rate K=32 PV:
//   S^T = K @ Q^T  via mfma_16x16x32 (A=K from LDS, B=Q in regs)
//   P^T = exp(S^T)*mask  — C-frags packed as ds_write_b64 into per-wave
//     Ps[query][key] (8 writes/wave-tile vs r5's 32 scalar b16)
//   O^T = V^T @ P^T via mfma_16x16x32 (A=V^T b128 from Vs, B=P^T b128 from Ps)
// 256 blocks (1/CU): grid=(8,16,2), 256 thr / 4 waves, wave = 64 queries —
// each K/V tile staged once serves 256 queries (4x amortization vs r5).
// Double-buffered K/V + reg prefetch, lgkm-only barrier (r5/r7-proven).
// Absolute-exp softmax (Q pre-scaled 1/8; masked p -> 0 via *mask).
// Fuses +q residual & per-head LN. Writes fp32 X and bf16 Xb.
// ---------------------------------------------------------------------------
__global__ __launch_bounds__(256, 2) void attn_mfma_kernel(
    const short* __restrict__ Qb, const short* __restrict__ Kb, const short* __restrict__ Vt,
    const float* __restrict__ Qf, const int* __restrict__ mask,
    const float* __restrict__ g_att, const float* __restrict__ b_att,
    float* __restrict__ X, short* __restrict__ Xb)
{
    const int tid  = threadIdx.x;
    const int lane = tid & 63;
    const int wave = tid >> 6;          // 0..3
    const int quad = lane >> 4;
    const int l15  = lane & 15;

    const int h  = blockIdx.y;
    const int b  = blockIdx.z;
    const int q0 = blockIdx.x * 256;    // block covers 256 queries
    const int qw0 = q0 + wave * 64;     // wave covers 64 queries
    const int bS = b * SS;

    __shared__ __align__(16) short Ks[2 * 64 * 72];   // [buf][key][d]
    __shared__ __align__(16) short Vs[2 * 64 * 72];   // [buf][d][key]
    __shared__ __align__(16) short Ps[4 * 64 * 72];   // per-wave [query][key]
    __shared__ __align__(16) float smv[2 * 64];       // [buf][key] mask 0/1

    short* Pw = &Ps[wave * 64 * 72];

    // Q fragments (bf16, pre-scaled 1/8) — MFMA B operand for S^T
    short8 qf[4][2];
#pragma unroll
    for (int qt = 0; qt < 4; qt++)
#pragma unroll
        for (int s = 0; s < 2; s++)
            qf[qt][s] = *(const short8*)(Qb +
                (size_t)(bS + qw0 + qt * 16 + l15) * DD + h * 64 + s * 32 + quad * 8);

    floatx4 o[4][4];                    // O^T tiles [dt][qt]
#pragma unroll
    for (int dt = 0; dt < 4; dt++)
#pragma unroll
        for (int qt = 0; qt < 4; qt++) o[dt][qt] = (floatx4)0.0f;
    float lsum[4] = {0.0f, 0.0f, 0.0f, 0.0f};

    const int srow = tid >> 3;          // staging row (+32 for i=1), 0..31
    const int sch  = tid & 7;

    // preload tile 0 into regs
    short8 kreg[2], vreg[2];
    float mreg;
#pragma unroll
    for (int i = 0; i < 2; i++) {
        int row = srow + i * 32;
        kreg[i] = *(const short8*)(Kb + (size_t)(bS + row) * DD + h * 64 + sch * 8);
        vreg[i] = *(const short8*)(Vt + (size_t)(b * 1024 + h * 64 + row) * SS + sch * 8);
    }
    mreg = (tid < 64) ? (float)mask[bS + tid] : 0.0f;

    for (int kt = 0; kt < SS / 64; kt++) {
        const int bufo = (kt & 1) * (64 * 72);
        const int mvo  = (kt & 1) * 64;
        // commit staged regs for tile kt (implicit vmcnt wait on kreg/vreg)
#pragma unroll
        for (int i = 0; i < 2; i++) {
            int row = srow + i * 32;
            *(short8*)&Ks[bufo + row * 72 + sch * 8] = kreg[i];
            *(short8*)&Vs[bufo + row * 72 + sch * 8] = vreg[i];
        }
        if (tid < 64) smv[mvo + tid] = mreg;

        // prefetch tile kt+1 (stays in flight across the barrier)
        if (kt < SS / 64 - 1) {
            const int k0n = (kt + 1) * 64;
#pragma unroll
            for (int i = 0; i < 2; i++) {
                int row = srow + i * 32;
                kreg[i] = *(const short8*)(Kb + (size_t)(bS + k0n + row) * DD + h * 64 + sch * 8);
                vreg[i] = *(const short8*)(Vt + (size_t)(b * 1024 + h * 64 + row) * SS + k0n + sch * 8);
            }
            mreg = (tid < 64) ? (float)mask[bS + k0n + tid] : 0.0f;
        }

        // raw barrier: drain LDS writes only; vmcnt stays in flight
        __builtin_amdgcn_s_waitcnt(0xC07F);
        __builtin_amdgcn_s_barrier();

        // S^T = K @ Q^T, P^T = exp(.)*mask, packed b64 into Ps[query][key]
#pragma unroll
        for (int kt4 = 0; kt4 < 4; kt4++) {
            short8 kf0 = *(const short8*)&Ks[bufo + (kt4 * 16 + l15) * 72 + quad * 8];
            short8 kf1 = *(const short8*)&Ks[bufo + (kt4 * 16 + l15) * 72 + 32 + quad * 8];
            floatx4 mv = *(const floatx4*)&smv[mvo + kt4 * 16 + quad * 4];
#pragma unroll
            for (int qt = 0; qt < 4; qt++) {
                floatx4 st = (floatx4)0.0f;
                st = __builtin_amdgcn_mfma_f32_16x16x32_bf16(kf0, qf[qt][0], st, 0, 0, 0);
                st = __builtin_amdgcn_mfma_f32_16x16x32_bf16(kf1, qf[qt][1], st, 0, 0, 0);
                short4v pk;
#pragma unroll
                for (int r = 0; r < 4; r++) {
                    float p = __expf(st[r]) * mv[r];
                    lsum[qt] += p;
                    pk[r] = f2bf(p);
                }
                *(short4v*)&Pw[(qt * 16 + l15) * 72 + kt4 * 16 + quad * 4] = pk;
            }
        }

        // O^T += V^T @ P^T  (both operands b128 from LDS, K=32 full rate)
#pragma unroll
        for (int s = 0; s < 2; s++) {
            short8 pb[4];
#pragma unroll
            for (int qt = 0; qt < 4; qt++)
                pb[qt] = *(const short8*)&Pw[(qt * 16 + l15) * 72 + s * 32 + quad * 8];
#pragma unroll
            for (int dt = 0; dt < 4; dt++) {
                short8 vf = *(const short8*)&Vs[bufo + (dt * 16 + l15) * 72 + s * 32 + quad * 8];
#pragma unroll
                for (int qt = 0; qt < 4; qt++)
                    o[dt][qt] = __builtin_amdgcn_mfma_f32_16x16x32_bf16(vf, pb[qt], o[dt][qt], 0, 0, 0);
            }
        }
    }

    // softmax denominators: complete the key-sum across quads
#pragma unroll
    for (int qt = 0; qt < 4; qt++) {
        lsum[qt] += __shfl_xor(lsum[qt], 16);
        lsum[qt] += __shfl_xor(lsum[qt], 32);
    }

    // epilogue: O/l + residual q (fp32), per-head LayerNorm over d=64
#pragma unroll
    for (int qt = 0; qt < 4; qt++) {
        const int q = qw0 + qt * 16 + l15;
        const size_t base = (size_t)(bS + q) * DD + h * 64;
        const float rl = 1.0f / lsum[qt];

        float x[4][4];
        float sum = 0.0f;
#pragma unroll
        for (int dt = 0; dt < 4; dt++) {
            float4 qr = ld4(Qf + base + dt * 16 + quad * 4);
            x[dt][0] = o[dt][qt][0] * rl + qr.x;
            x[dt][1] = o[dt][qt][1] * rl + qr.y;
            x[dt][2] = o[dt][qt][2] * rl + qr.z;
            x[dt][3] = o[dt][qt][3] * rl + qr.w;
            sum += x[dt][0] + x[dt][1] + x[dt][2] + x[dt][3];
        }
        sum += __shfl_xor(sum, 16);
        sum += __shfl_xor(sum, 32);
        const float mu = sum * (1.0f / 64.0f);

        float vs = 0.0f;
#pragma unroll
        for (int dt = 0; dt < 4; dt++)
#pragma unroll
            for (int r = 0; r < 4; r++) { float d = x[dt][r] - mu; vs += d * d; }
        vs += __shfl_xor(vs, 16);
        vs += __shfl_xor(vs, 32);
        const float rstd = rsqrtf(vs * (1.0f / 64.0f) + 1e-5f);

#pragma unroll
        for (int dt = 0; dt < 4; dt++) {
            float4 gv = ld4(g_att + dt * 16 + quad * 4);
            float4 bv = ld4(b_att + dt * 16 + quad * 4);
            float4 y;
            y.x = (x[dt][0] - mu) * rstd * gv.x + bv.x;
            y.y = (x[dt][1] - mu) * rstd * gv.y + bv.y;
            y.z = (x[dt][2] - mu) * rstd * gv.z + bv.z;
            y.w = (x[dt][3] - mu) * rstd * gv.w + bv.w;
            *(float4*)(X + base + dt * 16 + quad * 4) = y;
            short4v yb;
            yb[0] = f2bf(y.x); yb[1] = f2bf(y.y); yb[2] = f2bf(y.z); yb[3] = f2bf(y.w);
            *(short4v*)(Xb + base + dt * 16 + quad * 4) = yb;
        }
    }
}

// ---------------------------------------------------------------------------
// Final fused epilogue: Z = X + tanh(Y);  out = tanh(LayerNorm(Z, g, b))
// ---------------------------------------------------------------------------
__global__ __launch_bounds__(256) void lnout_kernel(
    const float* __restrict__ X, const float* __restrict__ Y,
    const float* __restrict__ g, const float* __restrict__ bcoef,
    float* __restrict__ out)
{
    const int r = blockIdx.x;
    const int t = threadIdx.x;
    const size_t base = (size_t)r * DD + (t << 2);
    float4 x = ld4(X + base);
    float4 y = ld4(Y + base);
    float4 z;
    z.x = x.x + tanhf(y.x);
    z.y = x.y + tanhf(y.y);
    z.z = x.z + tanhf(y.z);
    z.w = x.w + tanhf(y.w);

    __shared__ float red[4];
    __shared__ float stats[2];
    const int w = t >> 6;

    float sv = z.x + z.y + z.z + z.w;
#pragma unroll
    for (int off = 32; off > 0; off >>= 1) sv += __shfl_down(sv, off);
    if ((t & 63) == 0) red[w] = sv;
    __syncthreads();
    if (t == 0) stats[0] = (red[0] + red[1] + red[2] + red[3]) * (1.0f / 1024.0f);
    __syncthreads();
    const float mu = stats[0];

    float4 d;
    d.x = z.x - mu; d.y = z.y - mu; d.z = z.z - mu; d.w = z.w - mu;
    float s2 = d.x * d.x + d.y * d.y + d.z * d.z + d.w * d.w;
#pragma unroll
    for (int off = 32; off > 0; off >>= 1) s2 += __shfl_down(s2, off);
    if ((t & 63) == 0) red[w] = s2;
    __syncthreads();
    if (t == 0) stats[1] = rsqrtf((red[0] + red[1] + red[2] + red[3]) * (1.0f / 1024.0f) + 1e-5f);
    __syncthreads();
    const float rstd = stats[1];

    float4 gv = ld4(g + (t << 2));
    float4 bv = ld4(bcoef + (t << 2));
    float4 o;
    o.x = tanhf(d.x * rstd * gv.x + bv.x);
    o.y = tanhf(d.y * rstd * gv.y + bv.y);
    o.z = tanhf(d.z * rstd * gv.z + bv.z);
    o.w = tanhf(d.w * rstd * gv.w + bv.w);
    *(float4*)(out + base) = o;
}

// ---------------------------------------------------------------------------
extern "C" void kernel_launch(void* const* d_in, const int* in_sizes, int n_in,
                              void* d_out, int out_size, void* d_ws, size_t ws_size,
                              hipStream_t stream)
{
    const float* query = (const float*)d_in[0];
    const float* key   = (const float*)d_in[1];
    const float* value = (const float*)d_in[2];
    const int*   mask  = (const int*)  d_in[3];
    const float* Wq    = (const float*)d_in[4];
    const float* bq    = (const float*)d_in[5];
    const float* Wk    = (const float*)d_in[6];
    const float* bk    = (const float*)d_in[7];
    const float* Wv    = (const float*)d_in[8];
    const float* bv    = (const float*)d_in[9];
    const float* g_att = (const float*)d_in[10];
    const float* b_att = (const float*)d_in[11];
    const float* Wres  = (const float*)d_in[12];
    const float* bres  = (const float*)d_in[13];
    const float* g_out = (const float*)d_in[14];
    const float* b_out = (const float*)d_in[15];

    const size_t MAT = (size_t)MROWS * DD;     // 4M elements
    float* fws = (float*)d_ws;
    // fp32 regions
    float* Qw = fws;                           // fp32 Q residual
    float* Xw = fws + MAT;                     // attn out fp32
    // bf16 persistent regions
    short* Qb  = (short*)(fws + 2 * MAT);      // bf16 Q/8
    short* Kb  = Qb + MAT;
    short* Vt  = Kb + MAT;                     // V^T [(b*1024+h*64+d)][S]
    short* qbf = Vt + MAT;                     // bf16 GEMM inputs (dead after QKV)
    short* kbf = qbf + MAT;
    short* vbf = kbf + MAT;
    short* Wtq = vbf + MAT;                    // weight transposes
    short* Wtk = Wtq + DD * DD;
    short* Wtv = Wtk + DD * DD;
    short* Wtr = Wtv + DD * DD;
    // aliases (stream-ordered safe):
    short* Vb = (short*)Xw;                    // row-major bf16 V (dead before attn writes Xw)
    short* Xb = qbf;                           // attn bf16 out (qbf dead after QKV GEMM)
    float* Yw = (float*)kbf;                   // res GEMM fp32 out (kbf+vbf dead)

    // 1) fp32 -> bf16 activations
    convert_kernel<<<dim3(MAT / 2048, 1, 3), 256, 0, stream>>>(
        query, key, value, qbf, kbf, vbf);

    // 2) weight transpose-converts
    transpose_w_kernel<<<dim3(16, 16, 4), 256, 0, stream>>>(
        Wq, Wk, Wv, Wres, Wtq, Wtk, Wtv, Wtr);

    // 3) QKV projections. Q: fp32 + bf16*(1/8); K: bf16; V: bf16 ROW-MAJOR
    gemm_bf16_kernel<<<dim3(8, 32, 3), 256, 0, stream>>>(
        qbf, kbf, vbf, Wtq, Wtk, Wtv, bq, bk, bv,
        Qw, nullptr, nullptr,
        Qb, Kb, Vb,
        0.125f, 1.0f, 1.0f);

    // 4) coalesced V transpose: Vb -> Vt
    transpose_v_kernel<<<dim3(64, 16), 256, 0, stream>>>(Vb, Vt);

    // 5) bf16 MFMA attention (256q/block, b64-P roundtrip, K=32 PV) + res + LN
    attn_mfma_kernel<<<dim3(SS / 256, HH, BB), 256, 0, stream>>>(
        Qb, Kb, Vt, Qw, mask, g_att, b_att, Xw, Xb);

    // 6) res branch GEMM: Yw = Xb @ Wres + bres (fp32 out)
    gemm_bf16_kernel<<<dim3(8, 32, 1), 256, 0, stream>>>(
        Xb, Xb, Xb, Wtr, Wtr, Wtr, bres, bres, bres,
        Yw, Yw, Yw, nullptr, nullptr, nullptr,
        1.0f, 1.0f, 1.0f);

    // 7) Z = X + tanh(Y); out = tanh(LN(Z))
    lnout_kernel<<<MROWS, 256, 0, stream>>>(Xw, Yw, g_out, b_out, (float*)d_out);
}